// Round 14
// baseline (1294.363 us; speedup 1.0000x reference)
//
#include <hip/hip_runtime.h>
#include <hip/hip_bf16.h>
#include <math.h>

#define DEV __device__ __forceinline__

typedef __attribute__((ext_vector_type(8))) short short8;
typedef __attribute__((ext_vector_type(4))) float floatx4;

DEV float b2f_lo(unsigned u) { return __uint_as_float(u << 16); }
DEV float b2f_hi(unsigned u) { return __uint_as_float(u & 0xffff0000u); }

#if __has_builtin(__builtin_amdgcn_exp2f)
DEV float fexp2_(float x) { return __builtin_amdgcn_exp2f(x); }
#else
DEV float fexp2_(float x) { return exp2f(x); }
#endif
#if __has_builtin(__builtin_amdgcn_rcpf)
DEV float frcp_(float x) { return __builtin_amdgcn_rcpf(x); }
#else
DEV float frcp_(float x) { return 1.f / x; }
#endif

// async global->LDS, 16B per lane; LDS dest = uniform base + lane*16
DEV void gl2lds16(const void* g, void* l) {
  __builtin_amdgcn_global_load_lds(
      (const __attribute__((address_space(1))) unsigned int*)g,
      (__attribute__((address_space(3))) unsigned int*)l, 16, 0, 0);
}

union U8 { uint4 u; __hip_bfloat16 h[8]; };

// ------- conv stem v2: LDS-staged rows; block=(f,n); thread = 4t x 32oc ------
__global__ __launch_bounds__(256) void conv_stem_nhwc(const float* __restrict__ x,
    const float* __restrict__ w, const float* __restrict__ bias,
    __hip_bfloat16* __restrict__ out) {
  __shared__ float sX[3][2052];
  __shared__ float sW[288];
  __shared__ float sB[32];
  const int tid = threadIdx.x;
  const int f = blockIdx.x, n = blockIdx.y;
  const float* xb = x + (size_t)n * 262144;

  for (int i = tid; i < 1536; i += 256) {
    int r = i >> 9, c4 = i & 511;
    int fi = 2 * f - 1 + r;
    float4 v = {0.f, 0.f, 0.f, 0.f};
    if (fi >= 0 && fi < 128) v = *(const float4*)&xb[fi * 2048 + c4 * 4];
    sX[r][1 + c4 * 4 + 0] = v.x;
    sX[r][1 + c4 * 4 + 1] = v.y;
    sX[r][1 + c4 * 4 + 2] = v.z;
    sX[r][1 + c4 * 4 + 3] = v.w;
  }
  if (tid < 3) { sX[tid][0] = 0.f; sX[tid][2049] = 0.f; }
  for (int i = tid; i < 288; i += 256) sW[i] = w[i];
  if (tid < 32) sB[tid] = bias[tid];
  __syncthreads();

  float xv[4][9];
#pragma unroll
  for (int q = 0; q < 4; ++q) {
    int t = tid + q * 256;
#pragma unroll
    for (int r = 0; r < 3; ++r)
#pragma unroll
      for (int dc = 0; dc < 3; ++dc)
        xv[q][r * 3 + dc] = sX[r][2 * t + dc];
  }
#pragma unroll
  for (int ocq = 0; ocq < 4; ++ocq) {
    float wr[8][9];
#pragma unroll
    for (int oo = 0; oo < 8; ++oo)
#pragma unroll
      for (int qq = 0; qq < 9; ++qq)
        wr[oo][qq] = sW[(ocq * 8 + oo) * 9 + qq];
#pragma unroll
    for (int q = 0; q < 4; ++q) {
      U8 o;
#pragma unroll
      for (int oo = 0; oo < 8; ++oo) {
        float acc = sB[ocq * 8 + oo];
#pragma unroll
        for (int qq = 0; qq < 9; ++qq) acc = fmaf(wr[oo][qq], xv[q][qq], acc);
        o.h[oo] = __float2bfloat16(acc);
      }
      int t = tid + q * 256;
      *(uint4*)&out[(((size_t)n * 64 + f) * 1024 + t) * 32 + ocq * 8] = o.u;
    }
  }
}

// ----- batched weight swizzle: 6 conv layers -> [buf][tap][oc][ic] bf16 ------
__global__ __launch_bounds__(256) void wtap_conv6(const float* __restrict__ w1,
    const float* __restrict__ w2, __hip_bfloat16* __restrict__ out) {
  int i = blockIdx.x * 256 + threadIdx.x;        // 0..55295
  if (i < 55296) {
    int b = i / 9216, r = i - b * 9216;
    int layer = b >> 1, which = b & 1;
    const float* src = (which ? w2 : w1) + layer * 9216;
    int tap = r >> 10, oc = (r >> 5) & 31, ic = r & 31;
    out[b * 9216 + r] = __float2bfloat16(src[(oc * 32 + ic) * 9 + tap]);
  }
}

// ------ residual conv 3x3 MFMA v2: 4 output f-rows per block -----------------
template <int ADD>
__global__ __launch_bounds__(256) void conv_mfma(const __hip_bfloat16* __restrict__ Hin,
    const __hip_bfloat16* __restrict__ wt,
    const float* __restrict__ cb, const float* __restrict__ bg,
    const float* __restrict__ bb, const float* __restrict__ bm,
    const float* __restrict__ bv, __hip_bfloat16* Hres) {
  __shared__ __hip_bfloat16 sIn[6 * 130 * 40];
  __hip_bfloat16* sOut = sIn;
  const int tid = threadIdx.x;
  const int tb = blockIdx.x, fb = blockIdx.y, n = blockIdx.z;
  const int t0 = tb * 128, f0 = fb * 4;
  const __hip_bfloat16* Hb = Hin + (size_t)n * 2097152;

  for (int c = tid; c < 3120; c += 256) {
    int rr = c / 520;
    int r2 = c - rr * 520;
    int p = r2 >> 2, icq = r2 & 3;
    int fi = f0 - 1 + rr;
    int tg = t0 + p - 1;
    uint4 v = {0, 0, 0, 0};
    if (fi >= 0 && fi < 64 && tg >= 0 && tg < 1024)
      v = *(const uint4*)&Hb[((size_t)fi * 1024 + tg) * 32 + icq * 8];
    *(uint4*)&sIn[(rr * 130 + p) * 40 + icq * 8] = v;
  }

  const int lane = tid & 63, wave = tid >> 6;
  const int fr = lane & 15, fq = lane >> 4;
  short8 bfrag[9][2];
#pragma unroll
  for (int tap = 0; tap < 9; ++tap)
#pragma unroll
    for (int j = 0; j < 2; ++j)
      bfrag[tap][j] = *(const short8*)&wt[(tap * 32 + j * 16 + fr) * 32 + fq * 8];

  __syncthreads();

  const int tw = wave * 32;
  floatx4 acc[4][2][2];
#pragma unroll
  for (int fp = 0; fp < 4; ++fp)
#pragma unroll
    for (int mi = 0; mi < 2; ++mi)
#pragma unroll
      for (int j = 0; j < 2; ++j) acc[fp][mi][j] = (floatx4){0.f, 0.f, 0.f, 0.f};

#pragma unroll
  for (int fp = 0; fp < 4; ++fp) {
#pragma unroll
    for (int mi = 0; mi < 2; ++mi) {
      int pbase = tw + mi * 16 + fr;
#pragma unroll
      for (int df = 0; df < 3; ++df)
#pragma unroll
        for (int dc = 0; dc < 3; ++dc) {
          short8 af =
              *(const short8*)&sIn[((fp + df) * 130 + pbase + dc) * 40 + fq * 8];
          acc[fp][mi][0] = __builtin_amdgcn_mfma_f32_16x16x32_bf16(
              af, bfrag[df * 3 + dc][0], acc[fp][mi][0], 0, 0, 0);
          acc[fp][mi][1] = __builtin_amdgcn_mfma_f32_16x16x32_bf16(
              af, bfrag[df * 3 + dc][1], acc[fp][mi][1], 0, 0, 0);
        }
    }
  }

  float sc0 = bg[fr] * rsqrtf(bv[fr] + 1e-5f);
  float sh0 = (cb[fr] - bm[fr]) * sc0 + bb[fr];
  float sc1 = bg[fr + 16] * rsqrtf(bv[fr + 16] + 1e-5f);
  float sh1 = (cb[fr + 16] - bm[fr + 16]) * sc1 + bb[fr + 16];

  __syncthreads();
#pragma unroll
  for (int fp = 0; fp < 4; ++fp)
#pragma unroll
    for (int mi = 0; mi < 2; ++mi)
#pragma unroll
      for (int j = 0; j < 2; ++j) {
        float sc = j ? sc1 : sc0, sh = j ? sh1 : sh0;
#pragma unroll
        for (int reg = 0; reg < 4; ++reg) {
          int t_l = tw + mi * 16 + fq * 4 + reg;
          sOut[(fp * 128 + t_l) * 40 + j * 16 + fr] =
              __float2bfloat16(acc[fp][mi][j][reg] * sc + sh);
        }
      }
  __syncthreads();

  for (int c = tid; c < 2048; c += 256) {
    int fp = c >> 9, rem = c & 511;
    int t_l = rem >> 2, icq = rem & 3;
    U8 y;
    y.u = *(uint4*)&sOut[(fp * 128 + t_l) * 40 + icq * 8];
    size_t addr = (((size_t)n * 64 + f0 + fp) * 1024 + t0 + t_l) * 32 + icq * 8;
    U8 o;
    if (ADD) {
      U8 r;
      r.u = *(const uint4*)&Hres[addr];
#pragma unroll
      for (int i = 0; i < 8; ++i)
        o.h[i] = __float2bfloat16(
            fmaxf(__bfloat162float(y.h[i]) + __bfloat162float(r.h[i]), 0.f));
    } else {
#pragma unroll
      for (int i = 0; i < 8; ++i)
        o.h[i] = __float2bfloat16(fmaxf(__bfloat162float(y.h[i]), 0.f));
    }
    *(uint4*)&Hres[addr] = o.u;
  }
}

// ------ LN over NHWC row (t,n): F=2048, k-order k' = f*32+ic, bf16 out -------
__global__ __launch_bounds__(256) void ln_nhwc(const __hip_bfloat16* __restrict__ H,
    const float* __restrict__ g, const float* __restrict__ b,
    __hip_bfloat16* __restrict__ xn) {
  int r = blockIdx.x;
  int t = r >> 4, n = r & 15;
  int tid = threadIdx.x;
  int f = tid >> 2, icq = tid & 3;
  U8 v;
  v.u = *(const uint4*)&H[(((size_t)n * 64 + f) * 1024 + t) * 32 + icq * 8];
  float xv[8];
  float sum = 0.f, ss = 0.f;
#pragma unroll
  for (int i = 0; i < 8; ++i) {
    xv[i] = __bfloat162float(v.h[i]);
    sum += xv[i];
    ss += xv[i] * xv[i];
  }
#pragma unroll
  for (int off = 32; off > 0; off >>= 1) {
    sum += __shfl_down(sum, off);
    ss  += __shfl_down(ss, off);
  }
  __shared__ float red[8];
  int lane = tid & 63, wave = tid >> 6;
  if (lane == 0) { red[wave] = sum; red[4 + wave] = ss; }
  __syncthreads();
  sum = red[0] + red[1] + red[2] + red[3];
  ss  = red[4] + red[5] + red[6] + red[7];
  float mean = sum * (1.f / 2048.f);
  float var = ss * (1.f / 2048.f) - mean * mean;
  float inv = rsqrtf(var + 1e-5f);
  U8 o;
#pragma unroll
  for (int i = 0; i < 8; ++i) {
    int cf = (icq * 8 + i) * 64 + f;
    o.h[i] = __float2bfloat16((xv[i] - mean) * inv * g[cf] + b[cf]);
  }
  *(uint4*)&xn[(size_t)r * 2048 + tid * 8] = o.u;
}

// -- wproj0 permuted transpose: Wp0t[p][k'=f*32+ic] = wproj0[ic*64+f][p] bf16 --
__global__ __launch_bounds__(256) void wt_perm0(const float* __restrict__ in,
    __hip_bfloat16* __restrict__ out) {
  int i = blockIdx.x * 256 + threadIdx.x;
  int p = i >> 11, kp = i & 2047;
  int ic = kp & 31, f = kp >> 5;
  out[i] = __float2bfloat16(in[(ic * 64 + f) * 256 + p]);
}

// -------- LayerNorm bf16 rows F=1024 -> bf16 out -----------------------------
__global__ __launch_bounds__(256) void ln_rows_h(const __hip_bfloat16* __restrict__ in,
    const float* __restrict__ g, const float* __restrict__ b,
    __hip_bfloat16* __restrict__ out) {
  int r = blockIdx.x;
  int tid = threadIdx.x;
  union { ushort4 u; __hip_bfloat16 h[4]; } iv;
  iv.u = *(const ushort4*)&in[(size_t)r * 1024 + tid * 4];
  float x0 = __bfloat162float(iv.h[0]);
  float x1 = __bfloat162float(iv.h[1]);
  float x2 = __bfloat162float(iv.h[2]);
  float x3 = __bfloat162float(iv.h[3]);
  float sum = x0 + x1 + x2 + x3;
  float ss = x0 * x0 + x1 * x1 + x2 * x2 + x3 * x3;
#pragma unroll
  for (int off = 32; off > 0; off >>= 1) {
    sum += __shfl_down(sum, off);
    ss  += __shfl_down(ss, off);
  }
  __shared__ float red[8];
  int lane = tid & 63, wave = tid >> 6;
  if (lane == 0) { red[wave] = sum; red[4 + wave] = ss; }
  __syncthreads();
  sum = red[0] + red[1] + red[2] + red[3];
  ss  = red[4] + red[5] + red[6] + red[7];
  float mean = sum * (1.f / 1024.f);
  float var = ss * (1.f / 1024.f) - mean * mean;
  float inv = rsqrtf(var + 1e-5f);
  float4 gv = *(const float4*)&g[tid * 4];
  float4 bv = *(const float4*)&b[tid * 4];
  union { ushort4 u; __hip_bfloat16 h[4]; } o;
  o.h[0] = __float2bfloat16((x0 - mean) * inv * gv.x + bv.x);
  o.h[1] = __float2bfloat16((x1 - mean) * inv * gv.y + bv.y);
  o.h[2] = __float2bfloat16((x2 - mean) * inv * gv.z + bv.z);
  o.h[3] = __float2bfloat16((x3 - mean) * inv * gv.w + bv.w);
  *(ushort4*)&out[(size_t)r * 1024 + tid * 4] = o.u;
}

// ------- weight convert+transpose (batched over z): (K x N) -> (N x K) bf16 --
__global__ __launch_bounds__(256) void wt_bf16(const float* __restrict__ in,
    __hip_bfloat16* __restrict__ out, int K, int N, int inStride, int outStride) {
  __shared__ float tile[32][33];
  int x = threadIdx.x, y0 = threadIdx.y;
  int bn = blockIdx.x * 32;
  int bk = blockIdx.y * 32;
  const float* src = in + (size_t)blockIdx.z * inStride;
  __hip_bfloat16* dst = out + (size_t)blockIdx.z * outStride;
#pragma unroll
  for (int i = 0; i < 4; ++i) {
    int yy = y0 + i * 8;
    tile[yy][x] = src[(size_t)(bk + yy) * N + bn + x];
  }
  __syncthreads();
#pragma unroll
  for (int i = 0; i < 4; ++i) {
    int yy = y0 + i * 8;
    dst[(size_t)(bn + yy) * K + bk + x] = __float2bfloat16(tile[x][yy]);
  }
}

// ---- expansion weight prep (batched): w (256 x korig*1024) fp32 ->
// ---- Bt[(d*512+j)*4+k][ck] bf16 (4096 x 256), k>=korig rows zeroed ----------
__global__ void wexp_prep(const float* __restrict__ in,
    __hip_bfloat16* __restrict__ out, int korig, int inStride, int outStride) {
  __shared__ float tile[32][33];
  int jt = blockIdx.x;
  int ckt = blockIdx.y;
  int z = blockIdx.z;
  int layer = z >> 3, dk = z & 7;
  int d = dk >> 2, k = dk & 3;
  const float* src = in + (size_t)layer * inStride;
  __hip_bfloat16* dst = out + (size_t)layer * outStride;
  int x = threadIdx.x, y0 = threadIdx.y;
  bool valid = (k < korig);
#pragma unroll
  for (int i = 0; i < 4; ++i) {
    int yy = y0 + i * 8;
    tile[yy][x] = valid
        ? src[(size_t)(ckt * 32 + yy) * (korig * 1024) + (d * korig + k) * 512 +
              jt * 32 + x]
        : 0.f;
  }
  __syncthreads();
#pragma unroll
  for (int i = 0; i < 4; ++i) {
    int yy = y0 + i * 8;
    dst[(size_t)((d * 512 + jt * 32 + yy) * 4 + k) * 256 + ckt * 32 + x] =
        __float2bfloat16(tile[x][yy]);
  }
}

// ---- cls_w (1024x30) fp32 -> Wct (32x1024) bf16, rows >=30 zero -------------
__global__ __launch_bounds__(256) void wct_prep(const float* __restrict__ in,
    __hip_bfloat16* __restrict__ out) {
  int i = blockIdx.x * 256 + threadIdx.x;
  int nn = i >> 10, kk = i & 1023;
  out[i] = __float2bfloat16(nn < 30 ? in[kk * 30 + nn] : 0.f);
}

// -------- bf16 MFMA GEMM, double-buffered LDS: C = A(MxK) @ Bt(NxK)^T --------
// One barrier per k-iter; prefetch into buf p^1 overlaps MFMA on buf p.
// If xnres != nullptr: columns with (col&3)==3 store xnres[row][col>>2]
// via coalesced LDS-staged 128x32 block.
__global__ __launch_bounds__(256) void gemm_bf16(const __hip_bfloat16* __restrict__ A,
    const __hip_bfloat16* __restrict__ Bt, __hip_bfloat16* __restrict__ C,
    const __hip_bfloat16* __restrict__ xnres, int M, int N, int K) {
  __shared__ __hip_bfloat16 As[2][4096];    // 2 x 8 KB
  __shared__ __hip_bfloat16 Bs[2][4096];
  const int tid = threadIdx.x;
  const int m0 = blockIdx.y * 128, n0 = blockIdx.x * 128;
  const int lane = tid & 63, wave = tid >> 6;
  const int wm = wave & 1, wn = wave >> 1;
  const int fr = lane & 15, fq = lane >> 4;
  const int srow = lane >> 2, sch = lane & 3;

  const __hip_bfloat16* ga0 = &A[(size_t)(m0 + wave * 32 + srow) * K + sch * 8];
  const __hip_bfloat16* ga1 = ga0 + (size_t)16 * K;
  const __hip_bfloat16* gb0 = &Bt[(size_t)(n0 + wave * 32 + srow) * K + sch * 8];
  const __hip_bfloat16* gb1 = gb0 + (size_t)16 * K;
  const int lofs0 = (wave * 32) * 32;
  const int lofs1 = (wave * 32 + 16) * 32;

  floatx4 acc[4][4];
#pragma unroll
  for (int i = 0; i < 4; ++i)
#pragma unroll
    for (int j = 0; j < 4; ++j)
      acc[i][j] = (floatx4){0.f, 0.f, 0.f, 0.f};

  // prologue: stage first k-chunk into buffer 0
  gl2lds16(ga0, &As[0][lofs0]);
  gl2lds16(ga1, &As[0][lofs1]);
  gl2lds16(gb0, &Bs[0][lofs0]);
  gl2lds16(gb1, &Bs[0][lofs1]);

  int p = 0;
  for (int k0 = 0; k0 < K; k0 += 32) {
    __syncthreads();                       // buf p complete (barrier drains vm)
    if (k0 + 32 < K) {                     // prefetch next chunk into buf p^1
      gl2lds16(ga0 + k0 + 32, &As[p ^ 1][lofs0]);
      gl2lds16(ga1 + k0 + 32, &As[p ^ 1][lofs1]);
      gl2lds16(gb0 + k0 + 32, &Bs[p ^ 1][lofs0]);
      gl2lds16(gb1 + k0 + 32, &Bs[p ^ 1][lofs1]);
    }
    const __hip_bfloat16* Ap = As[p];
    const __hip_bfloat16* Bp = Bs[p];
    short8 af[4], bf_[4];
#pragma unroll
    for (int i = 0; i < 4; ++i) {
      af[i]  = *(const short8*)&Ap[(wm * 64 + i * 16 + fr) * 32 + fq * 8];
      bf_[i] = *(const short8*)&Bp[(wn * 64 + i * 16 + fr) * 32 + fq * 8];
    }
#pragma unroll
    for (int i = 0; i < 4; ++i)
#pragma unroll
      for (int j = 0; j < 4; ++j)
        acc[i][j] = __builtin_amdgcn_mfma_f32_16x16x32_bf16(af[i], bf_[j],
                                                            acc[i][j], 0, 0, 0);
    p ^= 1;
  }

  const bool dofuse = (xnres != nullptr);
  if (dofuse) {
    // stage xnres[m0..m0+127][nq0..nq0+31] into As[0] (64B rows, coalesced)
    const int nq0 = n0 >> 2;
    __syncthreads();   // all MFMA LDS reads done before overwrite
    const __hip_bfloat16* gx =
        &xnres[(size_t)(m0 + wave * 32 + srow) * 1024 + nq0 + sch * 8];
    gl2lds16(gx, &As[0][lofs0]);
    gl2lds16(gx + (size_t)16 * 1024, &As[0][lofs1]);
    __syncthreads();
  }

#pragma unroll
  for (int i = 0; i < 4; ++i)
#pragma unroll
    for (int j = 0; j < 4; ++j)
#pragma unroll
      for (int reg = 0; reg < 4; ++reg) {
        int rloc = wm * 64 + i * 16 + fq * 4 + reg;
        int row = m0 + rloc;
        int col = n0 + wn * 64 + j * 16 + fr;
        __hip_bfloat16 val;
        if (dofuse && (fr & 3) == 3)
          val = As[0][rloc * 32 + wn * 16 + j * 4 + (fr >> 2)];
        else
          val = __float2bfloat16(acc[i][j][reg]);
        C[(size_t)row * N + col] = val;
      }
}

// ------- skinny classifier GEMM: out[n][t][30] = xnc(16384x1024) @ Wct^T -----
__global__ __launch_bounds__(256) void cls_gemm(const __hip_bfloat16* __restrict__ A,
    const __hip_bfloat16* __restrict__ Wct, float* __restrict__ out) {
  const int tid = threadIdx.x;
  const int lane = tid & 63, wave = tid >> 6;
  const int fr = lane & 15, fq = lane >> 4;
  const int m0 = (blockIdx.x * 4 + wave) * 16;
  floatx4 acc[2];
  acc[0] = (floatx4){0.f, 0.f, 0.f, 0.f};
  acc[1] = (floatx4){0.f, 0.f, 0.f, 0.f};
#pragma unroll 4
  for (int k0 = 0; k0 < 1024; k0 += 32) {
    short8 af = *(const short8*)&A[(size_t)(m0 + fr) * 1024 + k0 + fq * 8];
    short8 b0 = *(const short8*)&Wct[(size_t)fr * 1024 + k0 + fq * 8];
    short8 b1 = *(const short8*)&Wct[(size_t)(16 + fr) * 1024 + k0 + fq * 8];
    acc[0] = __builtin_amdgcn_mfma_f32_16x16x32_bf16(af, b0, acc[0], 0, 0, 0);
    acc[1] = __builtin_amdgcn_mfma_f32_16x16x32_bf16(af, b1, acc[1], 0, 0, 0);
  }
#pragma unroll
  for (int j = 0; j < 2; ++j) {
    int col = j * 16 + fr;
    if (col < 30) {
#pragma unroll
      for (int reg = 0; reg < 4; ++reg) {
        int row = m0 + fq * 4 + reg;
        int t = row >> 4, n = row & 15;
        out[(size_t)n * 30720 + t * 30 + col] = acc[j][reg];
      }
    }
  }
}

// ---------------- SRU bidirectional scan (uniform k4 layout) -----------------
__global__ __launch_bounds__(64) void sru_scan(const __hip_bfloat16* __restrict__ U,
    const float* __restrict__ vc, const float* __restrict__ bias,
    __hip_bfloat16* __restrict__ out) {
  int gid = blockIdx.x * 64 + threadIdx.x;
  int j = gid & 511;
  int n = (gid >> 9) & 15;
  int d = gid >> 13;
  const float NL2E = -1.44269504f;
  float vf2 = NL2E * vc[(d * 2 + 0) * 512 + j];
  float vr2 = NL2E * vc[(d * 2 + 1) * 512 + j];
  float bf2 = NL2E * bias[(d * 2 + 0) * 512 + j];
  float br2 = NL2E * bias[(d * 2 + 1) * 512 + j];

  const char* Ub = (const char*)(U + (size_t)n * 4096 + d * 2048) + (size_t)j * 8;
  char* Ob = (char*)(out + (size_t)n * 1024 + d * 512) + (size_t)j * 2;
  const int US = d ? -131072 : 131072;
  const int OS = d ? -32768 : 32768;
  int uoff = d ? 1023 * 131072 : 0;
  int ooff = d ? 1023 * 32768 : 0;

  uint2 B0[16], B1[16], B2[16], B3[16];
  float c = 0.f;

#define LOADC(UB)                                                         \
  {                                                                       \
    _Pragma("unroll") for (int ss = 0; ss < 16; ++ss) {                   \
      UB[ss] = *(const uint2*)(Ub + uoff);                                \
      uoff += US;                                                         \
    }                                                                     \
  }

#define COMPC(UB)                                                         \
  {                                                                       \
    _Pragma("unroll") for (int ss = 0; ss < 16; ++ss) {                   \
      uint2 uv = UB[ss];                                                  \
      float a0 = b2f_lo(uv.x), a1 = b2f_hi(uv.x), a2 = b2f_lo(uv.y);      \
      float rx = b2f_hi(uv.y);                                            \
      float A1 = fmaf(a1, NL2E, bf2);                                     \
      float f = frcp_(1.f + fexp2_(fmaf(vf2, c, A1)));                    \
      float c2 = fmaf(f, c - a0, a0);                                     \
      float A2 = fmaf(a2, NL2E, br2);                                     \
      float r = frcp_(1.f + fexp2_(fmaf(vr2, c2, A2)));                   \
      float y = fmaf(r, c2 - rx, rx);                                     \
      *(__hip_bfloat16*)(Ob + ooff) = __float2bfloat16(y);                \
      ooff += OS;                                                         \
      c = c2;                                                             \
    }                                                                     \
  }

  LOADC(B0);
  LOADC(B1);
  LOADC(B2);
  for (int cb = 0; cb < 64; cb += 4) {
    LOADC(B3);
    COMPC(B0);
    if (cb + 4 < 64) LOADC(B0);
    COMPC(B1);
    if (cb + 5 < 64) LOADC(B1);
    COMPC(B2);
    if (cb + 6 < 64) LOADC(B2);
    COMPC(B3);
  }
#undef LOADC
#undef COMPC
}

extern "C" void kernel_launch(void* const* d_in, const int* in_sizes, int n_in,
                              void* d_out, int out_size, void* d_ws, size_t ws_size,
                              hipStream_t stream) {
  const float* x        = (const float*)d_in[0];
  const float* conv0_w  = (const float*)d_in[1];
  const float* conv0_b  = (const float*)d_in[2];
  const float* rconv1_w = (const float*)d_in[3];
  const float* rconv1_b = (const float*)d_in[4];
  const float* rbn1_g   = (const float*)d_in[5];
  const float* rbn1_b   = (const float*)d_in[6];
  const float* rbn1_m   = (const float*)d_in[7];
  const float* rbn1_v   = (const float*)d_in[8];
  const float* rconv2_w = (const float*)d_in[9];
  const float* rconv2_b = (const float*)d_in[10];
  const float* rbn2_g   = (const float*)d_in[11];
  const float* rbn2_b   = (const float*)d_in[12];
  const float* rbn2_m   = (const float*)d_in[13];
  const float* rbn2_v   = (const float*)d_in[14];
  const float* ln0_g    = (const float*)d_in[15];
  const float* ln0_b    = (const float*)d_in[16];
  const float* wproj0   = (const float*)d_in[17];
  const float* w0       = (const float*)d_in[18];
  const float* vc0      = (const float*)d_in[19];
  const float* bias0    = (const float*)d_in[20];
  const float* ln_g     = (const float*)d_in[21];
  const float* ln_b     = (const float*)d_in[22];
  const float* wproj    = (const float*)d_in[23];
  const float* w        = (const float*)d_in[24];
  const float* vc       = (const float*)d_in[25];
  const float* bias     = (const float*)d_in[26];
  const float* cln_g    = (const float*)d_in[27];
  const float* cln_b    = (const float*)d_in[28];
  const float* cls_w    = (const float*)d_in[29];
  float* out = (float*)d_out;

  // Two 128 MiB arenas.
  float* Af = (float*)d_ws;
  float* Bf = Af + 33554432;
  __hip_bfloat16* Ah = (__hip_bfloat16*)Af;
  __hip_bfloat16* Bh = (__hip_bfloat16*)Bf;

  __hip_bfloat16* hA     = Ah;                 // NHWC h (64 MB)
  __hip_bfloat16* hB     = Bh;                 // NHWC temp
  __hip_bfloat16* wt_all = Ah + 62914560;      // 6 x 18 KB @ A+120MB
  __hip_bfloat16* Wp0t   = Ah + 52428800;      // 1 MB @ A+100MB

  // Bh layout (bytes): s2h 0-32M | xnc 32-64M | xn3 64-96M | tmp 96-104M |
  //                    W3p[3] 104-110M | W0p 110-112M | Wpt3[3] 112-113.5M
  __hip_bfloat16* s2h  = Bh;
  __hip_bfloat16* xnc  = Bh + 16777216;
  __hip_bfloat16* xn3  = Bh + 33554432;
  __hip_bfloat16* tmp  = Bh + 50331648;
  __hip_bfloat16* W3p  = Bh + 54525952;        // stride 1048576/layer
  __hip_bfloat16* W0p  = Bh + 57671680;
  __hip_bfloat16* Wpt3 = Bh + 58720256;        // stride 262144/layer
  __hip_bfloat16* xn0  = Bh;                   // layer0 LN out (64 MB)
  __hip_bfloat16* U    = Ah;                   // 128 MB (rows = 4096)
  __hip_bfloat16* Wct  = Ah;                   // 64 KB (end only)

  // ---- batched weight preps (hoisted) ----
  wtap_conv6<<<216, 256, 0, stream>>>(rconv1_w, rconv2_w, wt_all);
  wt_perm0<<<2048, 256, 0, stream>>>(wproj0, Wp0t);
  wexp_prep<<<dim3(16, 8, 8), dim3(32, 8), 0, stream>>>(w0, W0p, 4, 0, 0);
  wexp_prep<<<dim3(16, 8, 24), dim3(32, 8), 0, stream>>>(w, W3p, 3,
                                                         786432, 1048576);
  wt_bf16<<<dim3(8, 32, 3), dim3(32, 8), 0, stream>>>(wproj, Wpt3, 1024, 256,
                                                      262144, 262144);

  // ---- conv stem + residual blocks ----
  conv_stem_nhwc<<<dim3(64, 16), 256, 0, stream>>>(x, conv0_w, conv0_b, hA);
  for (int i = 0; i < 3; ++i) {
    conv_mfma<0><<<dim3(8, 16, 16), 256, 0, stream>>>(hA, wt_all + (i * 2) * 9216,
        rconv1_b + i * 32, rbn1_g + i * 32, rbn1_b + i * 32,
        rbn1_m + i * 32, rbn1_v + i * 32, hB);
    conv_mfma<1><<<dim3(8, 16, 16), 256, 0, stream>>>(hB, wt_all + (i * 2 + 1) * 9216,
        rconv2_b + i * 32, rbn2_g + i * 32, rbn2_b + i * 32,
        rbn2_m + i * 32, rbn2_v + i * 32, hA);
  }

  // ---- SRU layer 0 (k=4, F=2048) ----
  ln_nhwc<<<16384, 256, 0, stream>>>(hA, ln0_g, ln0_b, xn0);
  gemm_bf16<<<dim3(2, 128), 256, 0, stream>>>(xn0, Wp0t, tmp, nullptr,
                                              16384, 256, 2048);
  gemm_bf16<<<dim3(32, 128), 256, 0, stream>>>(tmp, W0p, U, nullptr,
                                               16384, 4096, 256);
  sru_scan<<<256, 64, 0, stream>>>(U, vc0, bias0, s2h);

  // ---- SRU layers 1..3 (k=3 padded to 4; res LDS-fused in exp GEMM) ----
  for (int i = 0; i < 3; ++i) {
    ln_rows_h<<<16384, 256, 0, stream>>>(s2h, ln_g + i * 1024, ln_b + i * 1024, xn3);
    gemm_bf16<<<dim3(2, 128), 256, 0, stream>>>(xn3, Wpt3 + i * 262144, tmp,
                                                nullptr, 16384, 256, 1024);
    gemm_bf16<<<dim3(32, 128), 256, 0, stream>>>(tmp, W3p + i * 1048576, U, xn3,
                                                 16384, 4096, 256);
    sru_scan<<<256, 64, 0, stream>>>(U, vc + i * 2048, bias + i * 2048, s2h);
  }

  // ---- final LN + classifier (skinny MFMA GEMM) ----
  ln_rows_h<<<16384, 256, 0, stream>>>(s2h, cln_g, cln_b, xnc);
  wct_prep<<<128, 256, 0, stream>>>(cls_w, Wct);
  cls_gemm<<<256, 256, 0, stream>>>(xnc, Wct, out);
}

// Round 15
// 1205.308 us; speedup vs baseline: 1.0739x; 1.0739x over previous
//
#include <hip/hip_runtime.h>
#include <hip/hip_bf16.h>
#include <math.h>

#define DEV __device__ __forceinline__

typedef __attribute__((ext_vector_type(8))) short short8;
typedef __attribute__((ext_vector_type(4))) float floatx4;

DEV float b2f_lo(unsigned u) { return __uint_as_float(u << 16); }
DEV float b2f_hi(unsigned u) { return __uint_as_float(u & 0xffff0000u); }

#if __has_builtin(__builtin_amdgcn_exp2f)
DEV float fexp2_(float x) { return __builtin_amdgcn_exp2f(x); }
#else
DEV float fexp2_(float x) { return exp2f(x); }
#endif
#if __has_builtin(__builtin_amdgcn_rcpf)
DEV float frcp_(float x) { return __builtin_amdgcn_rcpf(x); }
#else
DEV float frcp_(float x) { return 1.f / x; }
#endif

// async global->LDS, 16B per lane; LDS dest = uniform base + lane*16
DEV void gl2lds16(const void* g, void* l) {
  __builtin_amdgcn_global_load_lds(
      (const __attribute__((address_space(1))) unsigned int*)g,
      (__attribute__((address_space(3))) unsigned int*)l, 16, 0, 0);
}

union U8 { uint4 u; __hip_bfloat16 h[8]; };

// ------- conv stem v2: LDS-staged rows; block=(f,n); thread = 4t x 32oc ------
__global__ __launch_bounds__(256) void conv_stem_nhwc(const float* __restrict__ x,
    const float* __restrict__ w, const float* __restrict__ bias,
    __hip_bfloat16* __restrict__ out) {
  __shared__ float sX[3][2052];
  __shared__ float sW[288];
  __shared__ float sB[32];
  const int tid = threadIdx.x;
  const int f = blockIdx.x, n = blockIdx.y;
  const float* xb = x + (size_t)n * 262144;

  for (int i = tid; i < 1536; i += 256) {
    int r = i >> 9, c4 = i & 511;
    int fi = 2 * f - 1 + r;
    float4 v = {0.f, 0.f, 0.f, 0.f};
    if (fi >= 0 && fi < 128) v = *(const float4*)&xb[fi * 2048 + c4 * 4];
    sX[r][1 + c4 * 4 + 0] = v.x;
    sX[r][1 + c4 * 4 + 1] = v.y;
    sX[r][1 + c4 * 4 + 2] = v.z;
    sX[r][1 + c4 * 4 + 3] = v.w;
  }
  if (tid < 3) { sX[tid][0] = 0.f; sX[tid][2049] = 0.f; }
  for (int i = tid; i < 288; i += 256) sW[i] = w[i];
  if (tid < 32) sB[tid] = bias[tid];
  __syncthreads();

  float xv[4][9];
#pragma unroll
  for (int q = 0; q < 4; ++q) {
    int t = tid + q * 256;
#pragma unroll
    for (int r = 0; r < 3; ++r)
#pragma unroll
      for (int dc = 0; dc < 3; ++dc)
        xv[q][r * 3 + dc] = sX[r][2 * t + dc];
  }
#pragma unroll
  for (int ocq = 0; ocq < 4; ++ocq) {
    float wr[8][9];
#pragma unroll
    for (int oo = 0; oo < 8; ++oo)
#pragma unroll
      for (int qq = 0; qq < 9; ++qq)
        wr[oo][qq] = sW[(ocq * 8 + oo) * 9 + qq];
#pragma unroll
    for (int q = 0; q < 4; ++q) {
      U8 o;
#pragma unroll
      for (int oo = 0; oo < 8; ++oo) {
        float acc = sB[ocq * 8 + oo];
#pragma unroll
        for (int qq = 0; qq < 9; ++qq) acc = fmaf(wr[oo][qq], xv[q][qq], acc);
        o.h[oo] = __float2bfloat16(acc);
      }
      int t = tid + q * 256;
      *(uint4*)&out[(((size_t)n * 64 + f) * 1024 + t) * 32 + ocq * 8] = o.u;
    }
  }
}

// ----- batched weight swizzle: 6 conv layers -> [buf][tap][oc][ic] bf16 ------
__global__ __launch_bounds__(256) void wtap_conv6(const float* __restrict__ w1,
    const float* __restrict__ w2, __hip_bfloat16* __restrict__ out) {
  int i = blockIdx.x * 256 + threadIdx.x;        // 0..55295
  if (i < 55296) {
    int b = i / 9216, r = i - b * 9216;
    int layer = b >> 1, which = b & 1;
    const float* src = (which ? w2 : w1) + layer * 9216;
    int tap = r >> 10, oc = (r >> 5) & 31, ic = r & 31;
    out[b * 9216 + r] = __float2bfloat16(src[(oc * 32 + ic) * 9 + tap]);
  }
}

// ------ residual conv 3x3 MFMA v2: 4 output f-rows per block -----------------
template <int ADD>
__global__ __launch_bounds__(256) void conv_mfma(const __hip_bfloat16* __restrict__ Hin,
    const __hip_bfloat16* __restrict__ wt,
    const float* __restrict__ cb, const float* __restrict__ bg,
    const float* __restrict__ bb, const float* __restrict__ bm,
    const float* __restrict__ bv, __hip_bfloat16* Hres) {
  __shared__ __hip_bfloat16 sIn[6 * 130 * 40];
  __hip_bfloat16* sOut = sIn;
  const int tid = threadIdx.x;
  const int tb = blockIdx.x, fb = blockIdx.y, n = blockIdx.z;
  const int t0 = tb * 128, f0 = fb * 4;
  const __hip_bfloat16* Hb = Hin + (size_t)n * 2097152;

  for (int c = tid; c < 3120; c += 256) {
    int rr = c / 520;
    int r2 = c - rr * 520;
    int p = r2 >> 2, icq = r2 & 3;
    int fi = f0 - 1 + rr;
    int tg = t0 + p - 1;
    uint4 v = {0, 0, 0, 0};
    if (fi >= 0 && fi < 64 && tg >= 0 && tg < 1024)
      v = *(const uint4*)&Hb[((size_t)fi * 1024 + tg) * 32 + icq * 8];
    *(uint4*)&sIn[(rr * 130 + p) * 40 + icq * 8] = v;
  }

  const int lane = tid & 63, wave = tid >> 6;
  const int fr = lane & 15, fq = lane >> 4;
  short8 bfrag[9][2];
#pragma unroll
  for (int tap = 0; tap < 9; ++tap)
#pragma unroll
    for (int j = 0; j < 2; ++j)
      bfrag[tap][j] = *(const short8*)&wt[(tap * 32 + j * 16 + fr) * 32 + fq * 8];

  __syncthreads();

  const int tw = wave * 32;
  floatx4 acc[4][2][2];
#pragma unroll
  for (int fp = 0; fp < 4; ++fp)
#pragma unroll
    for (int mi = 0; mi < 2; ++mi)
#pragma unroll
      for (int j = 0; j < 2; ++j) acc[fp][mi][j] = (floatx4){0.f, 0.f, 0.f, 0.f};

#pragma unroll
  for (int fp = 0; fp < 4; ++fp) {
#pragma unroll
    for (int mi = 0; mi < 2; ++mi) {
      int pbase = tw + mi * 16 + fr;
#pragma unroll
      for (int df = 0; df < 3; ++df)
#pragma unroll
        for (int dc = 0; dc < 3; ++dc) {
          short8 af =
              *(const short8*)&sIn[((fp + df) * 130 + pbase + dc) * 40 + fq * 8];
          acc[fp][mi][0] = __builtin_amdgcn_mfma_f32_16x16x32_bf16(
              af, bfrag[df * 3 + dc][0], acc[fp][mi][0], 0, 0, 0);
          acc[fp][mi][1] = __builtin_amdgcn_mfma_f32_16x16x32_bf16(
              af, bfrag[df * 3 + dc][1], acc[fp][mi][1], 0, 0, 0);
        }
    }
  }

  float sc0 = bg[fr] * rsqrtf(bv[fr] + 1e-5f);
  float sh0 = (cb[fr] - bm[fr]) * sc0 + bb[fr];
  float sc1 = bg[fr + 16] * rsqrtf(bv[fr + 16] + 1e-5f);
  float sh1 = (cb[fr + 16] - bm[fr + 16]) * sc1 + bb[fr + 16];

  __syncthreads();
#pragma unroll
  for (int fp = 0; fp < 4; ++fp)
#pragma unroll
    for (int mi = 0; mi < 2; ++mi)
#pragma unroll
      for (int j = 0; j < 2; ++j) {
        float sc = j ? sc1 : sc0, sh = j ? sh1 : sh0;
#pragma unroll
        for (int reg = 0; reg < 4; ++reg) {
          int t_l = tw + mi * 16 + fq * 4 + reg;
          sOut[(fp * 128 + t_l) * 40 + j * 16 + fr] =
              __float2bfloat16(acc[fp][mi][j][reg] * sc + sh);
        }
      }
  __syncthreads();

  for (int c = tid; c < 2048; c += 256) {
    int fp = c >> 9, rem = c & 511;
    int t_l = rem >> 2, icq = rem & 3;
    U8 y;
    y.u = *(uint4*)&sOut[(fp * 128 + t_l) * 40 + icq * 8];
    size_t addr = (((size_t)n * 64 + f0 + fp) * 1024 + t0 + t_l) * 32 + icq * 8;
    U8 o;
    if (ADD) {
      U8 r;
      r.u = *(const uint4*)&Hres[addr];
#pragma unroll
      for (int i = 0; i < 8; ++i)
        o.h[i] = __float2bfloat16(
            fmaxf(__bfloat162float(y.h[i]) + __bfloat162float(r.h[i]), 0.f));
    } else {
#pragma unroll
      for (int i = 0; i < 8; ++i)
        o.h[i] = __float2bfloat16(fmaxf(__bfloat162float(y.h[i]), 0.f));
    }
    *(uint4*)&Hres[addr] = o.u;
  }
}

// ------ LN over NHWC row (t,n): F=2048, k-order k' = f*32+ic, bf16 out -------
__global__ __launch_bounds__(256) void ln_nhwc(const __hip_bfloat16* __restrict__ H,
    const float* __restrict__ g, const float* __restrict__ b,
    __hip_bfloat16* __restrict__ xn) {
  int r = blockIdx.x;
  int t = r >> 4, n = r & 15;
  int tid = threadIdx.x;
  int f = tid >> 2, icq = tid & 3;
  U8 v;
  v.u = *(const uint4*)&H[(((size_t)n * 64 + f) * 1024 + t) * 32 + icq * 8];
  float xv[8];
  float sum = 0.f, ss = 0.f;
#pragma unroll
  for (int i = 0; i < 8; ++i) {
    xv[i] = __bfloat162float(v.h[i]);
    sum += xv[i];
    ss += xv[i] * xv[i];
  }
#pragma unroll
  for (int off = 32; off > 0; off >>= 1) {
    sum += __shfl_down(sum, off);
    ss  += __shfl_down(ss, off);
  }
  __shared__ float red[8];
  int lane = tid & 63, wave = tid >> 6;
  if (lane == 0) { red[wave] = sum; red[4 + wave] = ss; }
  __syncthreads();
  sum = red[0] + red[1] + red[2] + red[3];
  ss  = red[4] + red[5] + red[6] + red[7];
  float mean = sum * (1.f / 2048.f);
  float var = ss * (1.f / 2048.f) - mean * mean;
  float inv = rsqrtf(var + 1e-5f);
  U8 o;
#pragma unroll
  for (int i = 0; i < 8; ++i) {
    int cf = (icq * 8 + i) * 64 + f;
    o.h[i] = __float2bfloat16((xv[i] - mean) * inv * g[cf] + b[cf]);
  }
  *(uint4*)&xn[(size_t)r * 2048 + tid * 8] = o.u;
}

// -- wproj0 permuted transpose: Wp0t[p][k'=f*32+ic] = wproj0[ic*64+f][p] bf16 --
__global__ __launch_bounds__(256) void wt_perm0(const float* __restrict__ in,
    __hip_bfloat16* __restrict__ out) {
  int i = blockIdx.x * 256 + threadIdx.x;
  int p = i >> 11, kp = i & 2047;
  int ic = kp & 31, f = kp >> 5;
  out[i] = __float2bfloat16(in[(ic * 64 + f) * 256 + p]);
}

// -------- LayerNorm bf16 rows F=1024 -> bf16 out -----------------------------
__global__ __launch_bounds__(256) void ln_rows_h(const __hip_bfloat16* __restrict__ in,
    const float* __restrict__ g, const float* __restrict__ b,
    __hip_bfloat16* __restrict__ out) {
  int r = blockIdx.x;
  int tid = threadIdx.x;
  union { ushort4 u; __hip_bfloat16 h[4]; } iv;
  iv.u = *(const ushort4*)&in[(size_t)r * 1024 + tid * 4];
  float x0 = __bfloat162float(iv.h[0]);
  float x1 = __bfloat162float(iv.h[1]);
  float x2 = __bfloat162float(iv.h[2]);
  float x3 = __bfloat162float(iv.h[3]);
  float sum = x0 + x1 + x2 + x3;
  float ss = x0 * x0 + x1 * x1 + x2 * x2 + x3 * x3;
#pragma unroll
  for (int off = 32; off > 0; off >>= 1) {
    sum += __shfl_down(sum, off);
    ss  += __shfl_down(ss, off);
  }
  __shared__ float red[8];
  int lane = tid & 63, wave = tid >> 6;
  if (lane == 0) { red[wave] = sum; red[4 + wave] = ss; }
  __syncthreads();
  sum = red[0] + red[1] + red[2] + red[3];
  ss  = red[4] + red[5] + red[6] + red[7];
  float mean = sum * (1.f / 1024.f);
  float var = ss * (1.f / 1024.f) - mean * mean;
  float inv = rsqrtf(var + 1e-5f);
  float4 gv = *(const float4*)&g[tid * 4];
  float4 bv = *(const float4*)&b[tid * 4];
  union { ushort4 u; __hip_bfloat16 h[4]; } o;
  o.h[0] = __float2bfloat16((x0 - mean) * inv * gv.x + bv.x);
  o.h[1] = __float2bfloat16((x1 - mean) * inv * gv.y + bv.y);
  o.h[2] = __float2bfloat16((x2 - mean) * inv * gv.z + bv.z);
  o.h[3] = __float2bfloat16((x3 - mean) * inv * gv.w + bv.w);
  *(ushort4*)&out[(size_t)r * 1024 + tid * 4] = o.u;
}

// ------- weight convert+transpose (batched over z): (K x N) -> (N x K) bf16 --
__global__ __launch_bounds__(256) void wt_bf16(const float* __restrict__ in,
    __hip_bfloat16* __restrict__ out, int K, int N, int inStride, int outStride) {
  __shared__ float tile[32][33];
  int x = threadIdx.x, y0 = threadIdx.y;
  int bn = blockIdx.x * 32;
  int bk = blockIdx.y * 32;
  const float* src = in + (size_t)blockIdx.z * inStride;
  __hip_bfloat16* dst = out + (size_t)blockIdx.z * outStride;
#pragma unroll
  for (int i = 0; i < 4; ++i) {
    int yy = y0 + i * 8;
    tile[yy][x] = src[(size_t)(bk + yy) * N + bn + x];
  }
  __syncthreads();
#pragma unroll
  for (int i = 0; i < 4; ++i) {
    int yy = y0 + i * 8;
    dst[(size_t)(bn + yy) * K + bk + x] = __float2bfloat16(tile[x][yy]);
  }
}

// ---- expansion weight prep (batched): w (256 x korig*1024) fp32 ->
// ---- Bt[(d*512+j)*4+k][ck] bf16 (4096 x 256), k>=korig rows zeroed ----------
__global__ void wexp_prep(const float* __restrict__ in,
    __hip_bfloat16* __restrict__ out, int korig, int inStride, int outStride) {
  __shared__ float tile[32][33];
  int jt = blockIdx.x;
  int ckt = blockIdx.y;
  int z = blockIdx.z;
  int layer = z >> 3, dk = z & 7;
  int d = dk >> 2, k = dk & 3;
  const float* src = in + (size_t)layer * inStride;
  __hip_bfloat16* dst = out + (size_t)layer * outStride;
  int x = threadIdx.x, y0 = threadIdx.y;
  bool valid = (k < korig);
#pragma unroll
  for (int i = 0; i < 4; ++i) {
    int yy = y0 + i * 8;
    tile[yy][x] = valid
        ? src[(size_t)(ckt * 32 + yy) * (korig * 1024) + (d * korig + k) * 512 +
              jt * 32 + x]
        : 0.f;
  }
  __syncthreads();
#pragma unroll
  for (int i = 0; i < 4; ++i) {
    int yy = y0 + i * 8;
    dst[(size_t)((d * 512 + jt * 32 + yy) * 4 + k) * 256 + ckt * 32 + x] =
        __float2bfloat16(tile[x][yy]);
  }
}

// ---- cls_w (1024x30) fp32 -> Wct (32x1024) bf16, rows >=30 zero -------------
__global__ __launch_bounds__(256) void wct_prep(const float* __restrict__ in,
    __hip_bfloat16* __restrict__ out) {
  int i = blockIdx.x * 256 + threadIdx.x;
  int nn = i >> 10, kk = i & 1023;
  out[i] = __float2bfloat16(nn < 30 ? in[kk * 30 + nn] : 0.f);
}

// -------- bf16 MFMA GEMM (m97 structure): C = A(MxK) @ Bt(NxK)^T -------------
// If xnres != nullptr: columns with (col&3)==3 store xnres[row][col>>2],
// fetched via a coalesced LDS-staged 128x32 block (reuses As after k-loop).
__global__ __launch_bounds__(256) void gemm_bf16(const __hip_bfloat16* __restrict__ A,
    const __hip_bfloat16* __restrict__ Bt, __hip_bfloat16* __restrict__ C,
    const __hip_bfloat16* __restrict__ xnres, int M, int N, int K) {
  __shared__ __hip_bfloat16 As[128 * 32];
  __shared__ __hip_bfloat16 Bs[128 * 32];
  const int tid = threadIdx.x;
  const int m0 = blockIdx.y * 128, n0 = blockIdx.x * 128;
  const int lane = tid & 63, wave = tid >> 6;
  const int wm = wave & 1, wn = wave >> 1;
  const int fr = lane & 15, fq = lane >> 4;
  const int srow = lane >> 2, sch = lane & 3;

  const __hip_bfloat16* ga0 = &A[(size_t)(m0 + wave * 32 + srow) * K + sch * 8];
  const __hip_bfloat16* ga1 = ga0 + (size_t)16 * K;
  const __hip_bfloat16* gb0 = &Bt[(size_t)(n0 + wave * 32 + srow) * K + sch * 8];
  const __hip_bfloat16* gb1 = gb0 + (size_t)16 * K;
  __hip_bfloat16* la0 = &As[(wave * 32) * 32];
  __hip_bfloat16* la1 = &As[(wave * 32 + 16) * 32];
  __hip_bfloat16* lb0 = &Bs[(wave * 32) * 32];
  __hip_bfloat16* lb1 = &Bs[(wave * 32 + 16) * 32];

  floatx4 acc[4][4];
#pragma unroll
  for (int i = 0; i < 4; ++i)
#pragma unroll
    for (int j = 0; j < 4; ++j)
      acc[i][j] = (floatx4){0.f, 0.f, 0.f, 0.f};

  for (int k0 = 0; k0 < K; k0 += 32) {
    __syncthreads();
    gl2lds16(ga0 + k0, la0);
    gl2lds16(ga1 + k0, la1);
    gl2lds16(gb0 + k0, lb0);
    gl2lds16(gb1 + k0, lb1);
    __syncthreads();

    short8 af[4], bf_[4];
#pragma unroll
    for (int i = 0; i < 4; ++i) {
      af[i]  = *(const short8*)&As[(wm * 64 + i * 16 + fr) * 32 + fq * 8];
      bf_[i] = *(const short8*)&Bs[(wn * 64 + i * 16 + fr) * 32 + fq * 8];
    }
#pragma unroll
    for (int i = 0; i < 4; ++i)
#pragma unroll
      for (int j = 0; j < 4; ++j)
        acc[i][j] = __builtin_amdgcn_mfma_f32_16x16x32_bf16(af[i], bf_[j],
                                                            acc[i][j], 0, 0, 0);
  }

  const bool dofuse = (xnres != nullptr);
  if (dofuse) {
    // stage xnres[m0..m0+127][nq0..nq0+31] into As (64B rows, coalesced)
    const int nq0 = n0 >> 2;
    __syncthreads();   // all MFMA LDS reads done before overwrite
    const __hip_bfloat16* gx =
        &xnres[(size_t)(m0 + wave * 32 + srow) * 1024 + nq0 + sch * 8];
    gl2lds16(gx, la0);
    gl2lds16(gx + (size_t)16 * 1024, la1);
    __syncthreads();
  }

#pragma unroll
  for (int i = 0; i < 4; ++i)
#pragma unroll
    for (int j = 0; j < 4; ++j)
#pragma unroll
      for (int reg = 0; reg < 4; ++reg) {
        int rloc = wm * 64 + i * 16 + fq * 4 + reg;
        int row = m0 + rloc;
        int col = n0 + wn * 64 + j * 16 + fr;
        __hip_bfloat16 val;
        if (dofuse && (fr & 3) == 3)
          val = As[rloc * 32 + wn * 16 + j * 4 + (fr >> 2)];
        else
          val = __float2bfloat16(acc[i][j][reg]);
        C[(size_t)row * N + col] = val;
      }
}

// ------- skinny classifier GEMM: out[n][t][30] = xnc(16384x1024) @ Wct^T -----
__global__ __launch_bounds__(256) void cls_gemm(const __hip_bfloat16* __restrict__ A,
    const __hip_bfloat16* __restrict__ Wct, float* __restrict__ out) {
  const int tid = threadIdx.x;
  const int lane = tid & 63, wave = tid >> 6;
  const int fr = lane & 15, fq = lane >> 4;
  const int m0 = (blockIdx.x * 4 + wave) * 16;
  floatx4 acc[2];
  acc[0] = (floatx4){0.f, 0.f, 0.f, 0.f};
  acc[1] = (floatx4){0.f, 0.f, 0.f, 0.f};
#pragma unroll 4
  for (int k0 = 0; k0 < 1024; k0 += 32) {
    short8 af = *(const short8*)&A[(size_t)(m0 + fr) * 1024 + k0 + fq * 8];
    short8 b0 = *(const short8*)&Wct[(size_t)fr * 1024 + k0 + fq * 8];
    short8 b1 = *(const short8*)&Wct[(size_t)(16 + fr) * 1024 + k0 + fq * 8];
    acc[0] = __builtin_amdgcn_mfma_f32_16x16x32_bf16(af, b0, acc[0], 0, 0, 0);
    acc[1] = __builtin_amdgcn_mfma_f32_16x16x32_bf16(af, b1, acc[1], 0, 0, 0);
  }
#pragma unroll
  for (int j = 0; j < 2; ++j) {
    int col = j * 16 + fr;
    if (col < 30) {
#pragma unroll
      for (int reg = 0; reg < 4; ++reg) {
        int row = m0 + fq * 4 + reg;
        int t = row >> 4, n = row & 15;
        out[(size_t)n * 30720 + t * 30 + col] = acc[j][reg];
      }
    }
  }
}

// ---------------- SRU bidirectional scan (uniform k4 layout) -----------------
__global__ __launch_bounds__(64) void sru_scan(const __hip_bfloat16* __restrict__ U,
    const float* __restrict__ vc, const float* __restrict__ bias,
    __hip_bfloat16* __restrict__ out) {
  int gid = blockIdx.x * 64 + threadIdx.x;
  int j = gid & 511;
  int n = (gid >> 9) & 15;
  int d = gid >> 13;
  const float NL2E = -1.44269504f;
  float vf2 = NL2E * vc[(d * 2 + 0) * 512 + j];
  float vr2 = NL2E * vc[(d * 2 + 1) * 512 + j];
  float bf2 = NL2E * bias[(d * 2 + 0) * 512 + j];
  float br2 = NL2E * bias[(d * 2 + 1) * 512 + j];

  const char* Ub = (const char*)(U + (size_t)n * 4096 + d * 2048) + (size_t)j * 8;
  char* Ob = (char*)(out + (size_t)n * 1024 + d * 512) + (size_t)j * 2;
  const int US = d ? -131072 : 131072;
  const int OS = d ? -32768 : 32768;
  int uoff = d ? 1023 * 131072 : 0;
  int ooff = d ? 1023 * 32768 : 0;

  uint2 B0[16], B1[16], B2[16], B3[16];
  float c = 0.f;

#define LOADC(UB)                                                         \
  {                                                                       \
    _Pragma("unroll") for (int ss = 0; ss < 16; ++ss) {                   \
      UB[ss] = *(const uint2*)(Ub + uoff);                                \
      uoff += US;                                                         \
    }                                                                     \
  }

#define COMPC(UB)                                                         \
  {                                                                       \
    _Pragma("unroll") for (int ss = 0; ss < 16; ++ss) {                   \
      uint2 uv = UB[ss];                                                  \
      float a0 = b2f_lo(uv.x), a1 = b2f_hi(uv.x), a2 = b2f_lo(uv.y);      \
      float rx = b2f_hi(uv.y);                                            \
      float A1 = fmaf(a1, NL2E, bf2);                                     \
      float f = frcp_(1.f + fexp2_(fmaf(vf2, c, A1)));                    \
      float c2 = fmaf(f, c - a0, a0);                                     \
      float A2 = fmaf(a2, NL2E, br2);                                     \
      float r = frcp_(1.f + fexp2_(fmaf(vr2, c2, A2)));                   \
      float y = fmaf(r, c2 - rx, rx);                                     \
      *(__hip_bfloat16*)(Ob + ooff) = __float2bfloat16(y);                \
      ooff += OS;                                                         \
      c = c2;                                                             \
    }                                                                     \
  }

  LOADC(B0);
  LOADC(B1);
  LOADC(B2);
  for (int cb = 0; cb < 64; cb += 4) {
    LOADC(B3);
    COMPC(B0);
    if (cb + 4 < 64) LOADC(B0);
    COMPC(B1);
    if (cb + 5 < 64) LOADC(B1);
    COMPC(B2);
    if (cb + 6 < 64) LOADC(B2);
    COMPC(B3);
  }
#undef LOADC
#undef COMPC
}

extern "C" void kernel_launch(void* const* d_in, const int* in_sizes, int n_in,
                              void* d_out, int out_size, void* d_ws, size_t ws_size,
                              hipStream_t stream) {
  const float* x        = (const float*)d_in[0];
  const float* conv0_w  = (const float*)d_in[1];
  const float* conv0_b  = (const float*)d_in[2];
  const float* rconv1_w = (const float*)d_in[3];
  const float* rconv1_b = (const float*)d_in[4];
  const float* rbn1_g   = (const float*)d_in[5];
  const float* rbn1_b   = (const float*)d_in[6];
  const float* rbn1_m   = (const float*)d_in[7];
  const float* rbn1_v   = (const float*)d_in[8];
  const float* rconv2_w = (const float*)d_in[9];
  const float* rconv2_b = (const float*)d_in[10];
  const float* rbn2_g   = (const float*)d_in[11];
  const float* rbn2_b   = (const float*)d_in[12];
  const float* rbn2_m   = (const float*)d_in[13];
  const float* rbn2_v   = (const float*)d_in[14];
  const float* ln0_g    = (const float*)d_in[15];
  const float* ln0_b    = (const float*)d_in[16];
  const float* wproj0   = (const float*)d_in[17];
  const float* w0       = (const float*)d_in[18];
  const float* vc0      = (const float*)d_in[19];
  const float* bias0    = (const float*)d_in[20];
  const float* ln_g     = (const float*)d_in[21];
  const float* ln_b     = (const float*)d_in[22];
  const float* wproj    = (const float*)d_in[23];
  const float* w        = (const float*)d_in[24];
  const float* vc       = (const float*)d_in[25];
  const float* bias     = (const float*)d_in[26];
  const float* cln_g    = (const float*)d_in[27];
  const float* cln_b    = (const float*)d_in[28];
  const float* cls_w    = (const float*)d_in[29];
  float* out = (float*)d_out;

  // Two 128 MiB arenas.
  float* Af = (float*)d_ws;
  float* Bf = Af + 33554432;
  __hip_bfloat16* Ah = (__hip_bfloat16*)Af;
  __hip_bfloat16* Bh = (__hip_bfloat16*)Bf;

  __hip_bfloat16* hA     = Ah;                 // NHWC h (64 MB)
  __hip_bfloat16* hB     = Bh;                 // NHWC temp
  __hip_bfloat16* wt_all = Ah + 62914560;      // 6 x 18 KB @ A+120MB
  __hip_bfloat16* Wp0t   = Ah + 52428800;      // 1 MB @ A+100MB

  __hip_bfloat16* s2h  = Bh;
  __hip_bfloat16* xnc  = Bh + 16777216;
  __hip_bfloat16* xn3  = Bh + 33554432;
  __hip_bfloat16* tmp  = Bh + 50331648;
  __hip_bfloat16* W3p  = Bh + 54525952;        // stride 1048576/layer
  __hip_bfloat16* W0p  = Bh + 57671680;
  __hip_bfloat16* Wpt3 = Bh + 58720256;        // stride 262144/layer
  __hip_bfloat16* xn0  = Bh;                   // layer0 LN out (64 MB)
  __hip_bfloat16* U    = Ah;                   // 128 MB (rows = 4096)
  __hip_bfloat16* Wct  = Ah;                   // 64 KB (end only)

  // ---- batched weight preps (hoisted) ----
  wtap_conv6<<<216, 256, 0, stream>>>(rconv1_w, rconv2_w, wt_all);
  wt_perm0<<<2048, 256, 0, stream>>>(wproj0, Wp0t);
  wexp_prep<<<dim3(16, 8, 8), dim3(32, 8), 0, stream>>>(w0, W0p, 4, 0, 0);
  wexp_prep<<<dim3(16, 8, 24), dim3(32, 8), 0, stream>>>(w, W3p, 3,
                                                         786432, 1048576);
  wt_bf16<<<dim3(8, 32, 3), dim3(32, 8), 0, stream>>>(wproj, Wpt3, 1024, 256,
                                                      262144, 262144);

  // ---- conv stem + residual blocks ----
  conv_stem_nhwc<<<dim3(64, 16), 256, 0, stream>>>(x, conv0_w, conv0_b, hA);
  for (int i = 0; i < 3; ++i) {
    conv_mfma<0><<<dim3(8, 16, 16), 256, 0, stream>>>(hA, wt_all + (i * 2) * 9216,
        rconv1_b + i * 32, rbn1_g + i * 32, rbn1_b + i * 32,
        rbn1_m + i * 32, rbn1_v + i * 32, hB);
    conv_mfma<1><<<dim3(8, 16, 16), 256, 0, stream>>>(hB, wt_all + (i * 2 + 1) * 9216,
        rconv2_b + i * 32, rbn2_g + i * 32, rbn2_b + i * 32,
        rbn2_m + i * 32, rbn2_v + i * 32, hA);
  }

  // ---- SRU layer 0 (k=4, F=2048) ----
  ln_nhwc<<<16384, 256, 0, stream>>>(hA, ln0_g, ln0_b, xn0);
  gemm_bf16<<<dim3(2, 128), 256, 0, stream>>>(xn0, Wp0t, tmp, nullptr,
                                              16384, 256, 2048);
  gemm_bf16<<<dim3(32, 128), 256, 0, stream>>>(tmp, W0p, U, nullptr,
                                               16384, 4096, 256);
  sru_scan<<<256, 64, 0, stream>>>(U, vc0, bias0, s2h);

  // ---- SRU layers 1..3 (k=3 padded to 4; res LDS-fused in exp GEMM) ----
  for (int i = 0; i < 3; ++i) {
    ln_rows_h<<<16384, 256, 0, stream>>>(s2h, ln_g + i * 1024, ln_b + i * 1024, xn3);
    gemm_bf16<<<dim3(2, 128), 256, 0, stream>>>(xn3, Wpt3 + i * 262144, tmp,
                                                nullptr, 16384, 256, 1024);
    gemm_bf16<<<dim3(32, 128), 256, 0, stream>>>(tmp, W3p + i * 1048576, U, xn3,
                                                 16384, 4096, 256);
    sru_scan<<<256, 64, 0, stream>>>(U, vc + i * 2048, bias + i * 2048, s2h);
  }

  // ---- final LN + classifier (skinny MFMA GEMM) ----
  ln_rows_h<<<16384, 256, 0, stream>>>(s2h, cln_g, cln_b, xnc);
  wct_prep<<<128, 256, 0, stream>>>(cls_w, Wct);
  cls_gemm<<<256, 256, 0, stream>>>(xnc, Wct, out);
}